// Round 1
// baseline (252.095 us; speedup 1.0000x reference)
//
#include <hip/hip_runtime.h>
#include <hip/hip_bf16.h>

// Problem: out[s,b,o] = sum_h in[s,b,h] * w[o,h]
// Flatten: A = [M=8192, K=1024] fp32 row-major (M = S*B)
//          W = [N=4096, K=1024] fp32 row-major  (this is B^T layout: gemm_bt)
//          C = [M, N] fp32 row-major
// Strategy: convert A,W -> bf16 in d_ws, then m97-style MFMA GEMM
// (128x128 tile, BK=64, global_load_lds width=16, 16x16x32 bf16 MFMA).

typedef __bf16 bf16x8_t __attribute__((ext_vector_type(8)));
typedef __bf16 bf16x4_t __attribute__((ext_vector_type(4)));
typedef float f32x4_t __attribute__((ext_vector_type(4)));

constexpr int M = 8192;
constexpr int N = 4096;
constexpr int K = 1024;
constexpr int BM = 128;
constexpr int BN = 128;
constexpr int BK = 64;

// ---------------- fp32 -> bf16 convert (4 elems/thread, float4 in, 8B out) ----
__global__ __launch_bounds__(256) void cvt_f32_bf16(const float* __restrict__ src,
                                                    __bf16* __restrict__ dst) {
    size_t i = ((size_t)blockIdx.x * 256 + threadIdx.x) * 4;
    float4 v = *(const float4*)(src + i);
    bf16x4_t o;
    o[0] = (__bf16)v.x;
    o[1] = (__bf16)v.y;
    o[2] = (__bf16)v.z;
    o[3] = (__bf16)v.w;
    *(bf16x4_t*)(dst + i) = o;
}

// ---------------- bf16 GEMM, B^T input ---------------------------------------
__global__ __launch_bounds__(256) void gemm_bt(const __bf16* __restrict__ A,
                                               const __bf16* __restrict__ B,
                                               float* __restrict__ C) {
    // LDS tiles: row-major, row stride BK (=64 bf16 = 128 B). NO padding:
    // global_load_lds requires LDS dst = wave-uniform base + lane*16.
    __shared__ __bf16 As[BM * BK];
    __shared__ __bf16 Bs[BN * BK];

    const int tid = threadIdx.x;
    const int lane = tid & 63;
    const int wave = tid >> 6;       // 4 waves, 2x2 grid
    const int wr = wave >> 1;        // wave row (0..1)
    const int wc = wave & 1;         // wave col (0..1)
    const int quad = lane >> 4;      // 0..3
    const int l16 = lane & 15;       // 0..15

    const int bm = blockIdx.y * BM;
    const int bn = blockIdx.x * BN;

    f32x4_t acc[4][4] = {};

    for (int k0 = 0; k0 < K; k0 += BK) {
        // Stage A tile: 128x64 bf16 = 16 KB = 4 rounds of (256 threads * 16 B).
        // Element chunk for thread t round r: e = r*2048 + t*8
        //   LDS byte offset = e*2 = r*4096 + wave*1024 + lane*16  (uniform+lane*16 OK)
#pragma unroll
        for (int r = 0; r < 4; ++r) {
            int e = r * 2048 + tid * 8;
            int row = e >> 6;        // /64
            int col = e & 63;
            __builtin_amdgcn_global_load_lds(
                (const __attribute__((address_space(1))) unsigned int*)(A + (size_t)(bm + row) * K + k0 + col),
                (__attribute__((address_space(3))) unsigned int*)(As + e),
                16, 0, 0);
        }
#pragma unroll
        for (int r = 0; r < 4; ++r) {
            int e = r * 2048 + tid * 8;
            int row = e >> 6;
            int col = e & 63;
            __builtin_amdgcn_global_load_lds(
                (const __attribute__((address_space(1))) unsigned int*)(B + (size_t)(bn + row) * K + k0 + col),
                (__attribute__((address_space(3))) unsigned int*)(Bs + e),
                16, 0, 0);
        }
        __syncthreads();  // drains vmcnt (global_load_lds) + lgkmcnt

        // 2 k-steps of 32 over the 64-deep tile
#pragma unroll
        for (int kk = 0; kk < BK; kk += 32) {
            bf16x8_t a[4], b[4];
            // A-frag layout: lane holds A[m = l16][k = quad*8 + j], j=0..7
#pragma unroll
            for (int i = 0; i < 4; ++i)
                a[i] = *(const bf16x8_t*)(As + (wr * 64 + i * 16 + l16) * BK + kk + quad * 8);
#pragma unroll
            for (int j = 0; j < 4; ++j)
                b[j] = *(const bf16x8_t*)(Bs + (wc * 64 + j * 16 + l16) * BK + kk + quad * 8);
#pragma unroll
            for (int i = 0; i < 4; ++i)
#pragma unroll
                for (int j = 0; j < 4; ++j)
                    acc[i][j] = __builtin_amdgcn_mfma_f32_16x16x32_bf16(a[i], b[j], acc[i][j], 0, 0, 0);
        }
        __syncthreads();
    }

    // Epilogue. C/D layout (verified m89/m91): col = lane&15, row = quad*4 + reg.
    const int crow0 = bm + wr * 64 + quad * 4;
    const int ccol0 = bn + wc * 64 + l16;
#pragma unroll
    for (int i = 0; i < 4; ++i)
#pragma unroll
        for (int j = 0; j < 4; ++j)
#pragma unroll
            for (int r = 0; r < 4; ++r)
                C[(size_t)(crow0 + i * 16 + r) * N + (ccol0 + j * 16)] = acc[i][j][r];
}

extern "C" void kernel_launch(void* const* d_in, const int* in_sizes, int n_in,
                              void* d_out, int out_size, void* d_ws, size_t ws_size,
                              hipStream_t stream) {
    const float* in_f32 = (const float*)d_in[0];   // [S,B,H] = [M,K]
    const float* w_f32  = (const float*)d_in[1];   // [OUT,H] = [N,K]
    float* out = (float*)d_out;                     // [M,N]

    __bf16* A_bf = (__bf16*)d_ws;                   // M*K*2 = 16.78 MB
    __bf16* W_bf = A_bf + (size_t)M * K;            // N*K*2 =  8.39 MB

    // convert A: M*K = 8388608 elems / 4 per thread / 256 per block = 8192 blocks
    cvt_f32_bf16<<<(M * (size_t)K) / (4 * 256), 256, 0, stream>>>(in_f32, A_bf);
    // convert W: N*K = 4194304 elems -> 4096 blocks
    cvt_f32_bf16<<<(N * (size_t)K) / (4 * 256), 256, 0, stream>>>(w_f32, W_bf);

    dim3 grid(N / BN, M / BM);   // (32, 64) = 2048 blocks
    gemm_bt<<<grid, 256, 0, stream>>>(A_bf, W_bf, out);
}

// Round 2
// 234.327 us; speedup vs baseline: 1.0758x; 1.0758x over previous
//
#include <hip/hip_runtime.h>
#include <hip/hip_bf16.h>

// out[s,b,o] = sum_h in[s,b,h] * w[o,h]
// A = [M=8192, K=1024] fp32, W = [N=4096, K=1024] fp32 (B^T layout), C = [M,N] fp32.
// Round 1 -> 2: XOR-swizzled LDS layout to kill the 2.5e7 bank-conflict cycles
// (fragment reads previously hit one 4-bank group per quad). Swizzle is applied
// by permuting the GLOBAL source chunk per lane (global_load_lds forces LDS
// dst = base + lane*16, so the LDS side cannot be swizzled directly).

typedef __bf16 bf16x8_t __attribute__((ext_vector_type(8)));
typedef float f32x4_t __attribute__((ext_vector_type(4)));

constexpr int M = 8192;
constexpr int N = 4096;
constexpr int K = 1024;
constexpr int BM = 128;
constexpr int BN = 128;
constexpr int BK = 64;

// ---------------- fp32 -> bf16 convert, both tensors in one launch ----------
// 8 elems/thread: two float4 loads, one 16B bf16x8 store. A|W boundary is
// block-aligned (M*K / 2048 = 4096 blocks), so the branch is block-uniform.
__global__ __launch_bounds__(256) void cvt_f32_bf16(const float* __restrict__ a,
                                                    const float* __restrict__ w,
                                                    __bf16* __restrict__ a_bf,
                                                    __bf16* __restrict__ w_bf) {
    size_t i = ((size_t)blockIdx.x * 256 + threadIdx.x) * 8;
    const float* src;
    __bf16* dst;
    if (i < (size_t)M * K) {
        src = a + i;
        dst = a_bf + i;
    } else {
        size_t j = i - (size_t)M * K;
        src = w + j;
        dst = w_bf + j;
    }
    float4 v0 = *(const float4*)(src);
    float4 v1 = *(const float4*)(src + 4);
    bf16x8_t o;
    o[0] = (__bf16)v0.x; o[1] = (__bf16)v0.y; o[2] = (__bf16)v0.z; o[3] = (__bf16)v0.w;
    o[4] = (__bf16)v1.x; o[5] = (__bf16)v1.y; o[6] = (__bf16)v1.z; o[7] = (__bf16)v1.w;
    *(bf16x8_t*)dst = o;
}

// ---------------- bf16 GEMM, B^T input, XOR-swizzled LDS --------------------
__global__ __launch_bounds__(256) void gemm_bt(const __bf16* __restrict__ A,
                                               const __bf16* __restrict__ B,
                                               float* __restrict__ C) {
    // Row stride 64 bf16 = 128 B = 8 chunks of 16 B. LDS slot (row, chunk c)
    // holds global chunk c ^ (row & 7).
    __shared__ __bf16 As[BM * BK];
    __shared__ __bf16 Bs[BN * BK];

    const int tid = threadIdx.x;
    const int lane = tid & 63;
    const int wave = tid >> 6;       // 4 waves, 2x2 grid
    const int wr = wave >> 1;
    const int wc = wave & 1;
    const int quad = lane >> 4;      // 0..3
    const int l16 = lane & 15;       // 0..15
    const int sa = l16 & 7;          // read-side swizzle key (= row & 7)

    const int bm = blockIdx.y * BM;
    const int bn = blockIdx.x * BN;

    f32x4_t acc[4][4] = {};

    for (int k0 = 0; k0 < K; k0 += BK) {
        // Stage 128x64 bf16 (16 KB) per matrix: 4 rounds x 256 threads x 16 B.
        // Thread t, round r: LDS element e = r*2048 + t*8 -> (row = e/64, chunk b = t&7).
        // Source chunk is b ^ (row&7); row&7 == (t>>3)&7 within a round.
#pragma unroll
        for (int r = 0; r < 4; ++r) {
            int e = r * 2048 + tid * 8;
            int row = e >> 6;
            int src_col = ((tid & 7) ^ ((tid >> 3) & 7)) << 3;
            __builtin_amdgcn_global_load_lds(
                (const __attribute__((address_space(1))) unsigned int*)(A + (size_t)(bm + row) * K + k0 + src_col),
                (__attribute__((address_space(3))) unsigned int*)(As + e),
                16, 0, 0);
        }
#pragma unroll
        for (int r = 0; r < 4; ++r) {
            int e = r * 2048 + tid * 8;
            int row = e >> 6;
            int src_col = ((tid & 7) ^ ((tid >> 3) & 7)) << 3;
            __builtin_amdgcn_global_load_lds(
                (const __attribute__((address_space(1))) unsigned int*)(B + (size_t)(bn + row) * K + k0 + src_col),
                (__attribute__((address_space(3))) unsigned int*)(Bs + e),
                16, 0, 0);
        }
        __syncthreads();

#pragma unroll
        for (int kk = 0; kk < BK; kk += 32) {
            bf16x8_t a[4], b[4];
            // Want global col kk + quad*8 of row rr -> chunk (kk/8 + quad),
            // stored at swizzled chunk ((kk/8 + quad) ^ (rr & 7)); rr&7 == l16&7.
#pragma unroll
            for (int i = 0; i < 4; ++i) {
                int rr = wr * 64 + i * 16 + l16;
                int swz = ((kk >> 3) + quad) ^ sa;
                a[i] = *(const bf16x8_t*)(As + rr * BK + swz * 8);
            }
#pragma unroll
            for (int j = 0; j < 4; ++j) {
                int rr = wc * 64 + j * 16 + l16;
                int swz = ((kk >> 3) + quad) ^ sa;
                b[j] = *(const bf16x8_t*)(Bs + rr * BK + swz * 8);
            }
#pragma unroll
            for (int i = 0; i < 4; ++i)
#pragma unroll
                for (int j = 0; j < 4; ++j)
                    acc[i][j] = __builtin_amdgcn_mfma_f32_16x16x32_bf16(a[i], b[j], acc[i][j], 0, 0, 0);
        }
        __syncthreads();
    }

    // C/D layout (verified m89/m91): col = lane&15, row = quad*4 + reg.
    const int crow0 = bm + wr * 64 + quad * 4;
    const int ccol0 = bn + wc * 64 + l16;
#pragma unroll
    for (int i = 0; i < 4; ++i)
#pragma unroll
        for (int j = 0; j < 4; ++j)
#pragma unroll
            for (int r = 0; r < 4; ++r)
                C[(size_t)(crow0 + i * 16 + r) * N + (ccol0 + j * 16)] = acc[i][j][r];
}

extern "C" void kernel_launch(void* const* d_in, const int* in_sizes, int n_in,
                              void* d_out, int out_size, void* d_ws, size_t ws_size,
                              hipStream_t stream) {
    const float* in_f32 = (const float*)d_in[0];   // [M,K]
    const float* w_f32  = (const float*)d_in[1];   // [N,K]
    float* out = (float*)d_out;                     // [M,N]

    __bf16* A_bf = (__bf16*)d_ws;
    __bf16* W_bf = A_bf + (size_t)M * K;

    // (M*K + N*K) / (8 elems * 256 thr) = 6144 blocks
    cvt_f32_bf16<<<((size_t)(M + N) * K) / (8 * 256), 256, 0, stream>>>(in_f32, w_f32, A_bf, W_bf);

    dim3 grid(N / BN, M / BM);   // (32, 64) = 2048 blocks
    gemm_bt<<<grid, 256, 0, stream>>>(A_bf, W_bf, out);
}